// Round 1
// baseline (1515.254 us; speedup 1.0000x reference)
//
#include <hip/hip_runtime.h>

namespace {

constexpr int TT = 1024;   // timesteps
constexpr int NB = 4096;   // batch
constexpr int I0 = 5;
constexpr int H0 = 15, H1 = 10, H2 = 2;

// LDS row strides (floats): multiples of 4 (16B-aligned for b128 merges),
// non-multiples of 32 so 16-row broadcast reads alias <=2-way (free, m136).
constexpr int S_W0H = 20;  // w_hh0: 45 rows x 15
constexpr int S_W0X = 12;  // w_ih0: 45 rows x 5
constexpr int S_W1X = 20;  // w_ih1: 30 rows x 15
constexpr int S_W1H = 12;  // w_hh1: 30 rows x 10
constexpr int S_W2X = 12;  // w_ih2:  6 rows x 10
constexpr int S_W2H = 4;   // w_hh2:  6 rows x 2

__device__ __forceinline__ float frcp(float v) { return __builtin_amdgcn_rcpf(v); }
__device__ __forceinline__ float sigm(float v) { return frcp(1.0f + __expf(-v)); }
// tanh(v) = 2*sigmoid(2v)-1 : no inf/inf for large |v|
__device__ __forceinline__ float tanh_(float v) {
  return 2.0f * frcp(1.0f + __expf(-2.0f * v)) - 1.0f;
}

template <int R, int C, int ST>
__device__ void stage_w(float* dst, const float* __restrict__ src, int tid) {
  for (int i = tid; i < R * C; i += 64) {
    const int r = i / C;          // C is constexpr -> magic-mul
    const int c = i - r * C;
    dst[r * ST + c] = src[i];
  }
}

}  // namespace

// Grid: 1024 blocks x 64 threads. Block = 4 samples x 16 hidden-slots
// (single wave: barriers ~free, DS in-order per wave => no WAR hazards).
extern "C" __global__ __launch_bounds__(64) void gru3_fused(
    const float* __restrict__ x,
    const float* __restrict__ w_ih0, const float* __restrict__ w_hh0,
    const float* __restrict__ b_ih0, const float* __restrict__ b_hh0,
    const float* __restrict__ w_ih1, const float* __restrict__ w_hh1,
    const float* __restrict__ b_ih1, const float* __restrict__ b_hh1,
    const float* __restrict__ w_ih2, const float* __restrict__ w_hh2,
    const float* __restrict__ b_ih2, const float* __restrict__ b_hh2,
    float* __restrict__ out) {
  __shared__ float W0H[45 * S_W0H];
  __shared__ float W0X[45 * S_W0X];
  __shared__ float W1X[30 * S_W1X];
  __shared__ float W1H[30 * S_W1H];
  __shared__ float W2X[6 * S_W2X];
  __shared__ float W2H[6 * S_W2H];
  __shared__ float h0buf[64];   // [sample(4)][16]  cols >= H are pads
  __shared__ float h1buf[64];
  __shared__ float h2buf[64];

  const int tid  = threadIdx.x;
  const int slot = tid & 15;     // hidden-unit slot
  const int smp  = tid >> 4;     // sample-in-block 0..3
  const int b    = blockIdx.x * 4 + smp;
  const int hbase = smp << 4;

  stage_w<45, 15, S_W0H>(W0H, w_hh0, tid);
  stage_w<45,  5, S_W0X>(W0X, w_ih0, tid);
  stage_w<30, 15, S_W1X>(W1X, w_ih1, tid);
  stage_w<30, 10, S_W1H>(W1H, w_hh1, tid);
  stage_w< 6, 10, S_W2X>(W2X, w_ih2, tid);
  stage_w< 6,  2, S_W2H>(W2H, w_hh2, tid);
  h0buf[tid] = 0.0f;
  h1buf[tid] = 0.0f;
  h2buf[tid] = 0.0f;

  // Clamped row index per layer: extra slots duplicate the last hidden unit
  // (uniform control flow); their LDS writes land in pad columns (never read).
  const int c0 = slot < H0 ? slot : H0 - 1;
  const int c1 = slot < H1 ? slot : H1 - 1;
  const int c2 = slot < H2 ? slot : H2 - 1;

  // Biases: fold b_ih+b_hh for r,z; keep n-gate halves separate (r * (hn + b_hh_n)).
  const float b0r  = b_ih0[c0]          + b_hh0[c0];
  const float b0z  = b_ih0[H0 + c0]     + b_hh0[H0 + c0];
  const float b0nx = b_ih0[2 * H0 + c0];
  const float b0nh = b_hh0[2 * H0 + c0];
  const float b1r  = b_ih1[c1]          + b_hh1[c1];
  const float b1z  = b_ih1[H1 + c1]     + b_hh1[H1 + c1];
  const float b1nx = b_ih1[2 * H1 + c1];
  const float b1nh = b_hh1[2 * H1 + c1];
  const float b2r  = b_ih2[c2]          + b_hh2[c2];
  const float b2z  = b_ih2[H2 + c2]     + b_hh2[H2 + c2];
  const float b2nx = b_ih2[2 * H2 + c2];
  const float b2nh = b_hh2[2 * H2 + c2];

  // Per-slot weight row pointers (LDS broadcast reads inside the t-loop; the
  // per-step barriers keep these loads from being LICM-hoisted into registers).
  const float* w0r = &W0H[c0 * S_W0H];
  const float* w0z = &W0H[(H0 + c0) * S_W0H];
  const float* w0n = &W0H[(2 * H0 + c0) * S_W0H];
  const float* v0r = &W0X[c0 * S_W0X];
  const float* v0z = &W0X[(H0 + c0) * S_W0X];
  const float* v0n = &W0X[(2 * H0 + c0) * S_W0X];
  const float* v1r = &W1X[c1 * S_W1X];
  const float* v1z = &W1X[(H1 + c1) * S_W1X];
  const float* v1n = &W1X[(2 * H1 + c1) * S_W1X];
  const float* w1r = &W1H[c1 * S_W1H];
  const float* w1z = &W1H[(H1 + c1) * S_W1H];
  const float* w1n = &W1H[(2 * H1 + c1) * S_W1H];
  const float* v2r = &W2X[c2 * S_W2X];
  const float* v2z = &W2X[(H2 + c2) * S_W2X];
  const float* v2n = &W2X[(2 * H2 + c2) * S_W2X];
  const float* w2r = &W2H[c2 * S_W2H];
  const float* w2z = &W2H[(H2 + c2) * S_W2H];
  const float* w2n = &W2H[(2 * H2 + c2) * S_W2H];

  // Replicated per-lane recurrent state (refreshed from LDS each step) and
  // each slot's own hidden value (avoids variable register indexing).
  float h0r[H0], h1r[H1], h2r[H2];
#pragma unroll
  for (int k = 0; k < H0; ++k) h0r[k] = 0.0f;
#pragma unroll
  for (int k = 0; k < H1; ++k) h1r[k] = 0.0f;
#pragma unroll
  for (int k = 0; k < H2; ++k) h2r[k] = 0.0f;
  float h0m = 0.0f, h1m = 0.0f, h2m = 0.0f;

  // x prefetch for t=0
  float xc[I0];
  {
    const float* xp = x + b * I0;  // t = 0
#pragma unroll
    for (int j = 0; j < I0; ++j) xc[j] = xp[j];
  }

  __syncthreads();  // staged weights visible

#pragma unroll 1
  for (int t = 0; t < TT; ++t) {
    // Prefetch next step's x (16 lanes share each address -> coalesced line).
    float xnx[I0];
    {
      const int tn = (t + 1 < TT) ? t + 1 : t;
      const float* xq = x + (tn * NB + b) * I0;
#pragma unroll
      for (int j = 0; j < I0; ++j) xnx[j] = xq[j];
    }

    // ---------------- layer 0 ----------------
    {
      float aR = b0r, aZ = b0z, aNx = b0nx, aNh = b0nh;
#pragma unroll
      for (int k = 0; k < H0; ++k) {
        const float h = h0r[k];
        aR += w0r[k] * h;
        aZ += w0z[k] * h;
        aNh += w0n[k] * h;
      }
#pragma unroll
      for (int j = 0; j < I0; ++j) {
        const float xv = xc[j];
        aR += v0r[j] * xv;
        aZ += v0z[j] * xv;
        aNx += v0n[j] * xv;
      }
      const float r = sigm(aR);
      const float z = sigm(aZ);
      const float n = tanh_(aNx + r * aNh);
      h0m = (1.0f - z) * n + z * h0m;
      h0buf[hbase + slot] = h0m;   // slot 15 -> pad col, never read
    }
    __syncthreads();
#pragma unroll
    for (int k = 0; k < H0; ++k) h0r[k] = h0buf[hbase + k];

    // ---------------- layer 1 ----------------
    {
      float aR = b1r, aZ = b1z, aNx = b1nx, aNh = b1nh;
#pragma unroll
      for (int k = 0; k < H0; ++k) {
        const float v = h0r[k];
        aR += v1r[k] * v;
        aZ += v1z[k] * v;
        aNx += v1n[k] * v;
      }
#pragma unroll
      for (int k = 0; k < H1; ++k) {
        const float v = h1r[k];
        aR += w1r[k] * v;
        aZ += w1z[k] * v;
        aNh += w1n[k] * v;
      }
      const float r = sigm(aR);
      const float z = sigm(aZ);
      const float n = tanh_(aNx + r * aNh);
      h1m = (1.0f - z) * n + z * h1m;
      h1buf[hbase + slot] = h1m;
    }
    __syncthreads();
#pragma unroll
    for (int k = 0; k < H1; ++k) h1r[k] = h1buf[hbase + k];

    // ---------------- layer 2 ----------------
    {
      float aR = b2r, aZ = b2z, aNx = b2nx, aNh = b2nh;
#pragma unroll
      for (int k = 0; k < H1; ++k) {
        const float v = h1r[k];
        aR += v2r[k] * v;
        aZ += v2z[k] * v;
        aNx += v2n[k] * v;
      }
#pragma unroll
      for (int k = 0; k < H2; ++k) {
        const float v = h2r[k];
        aR += w2r[k] * v;
        aZ += w2z[k] * v;
        aNh += w2n[k] * v;
      }
      const float r = sigm(aR);
      const float z = sigm(aZ);
      const float n = tanh_(aNx + r * aNh);
      h2m = (1.0f - z) * n + z * h2m;
      h2buf[hbase + slot] = h2m;
      if (slot < H2) {
        out[(t * NB + b) * H2 + slot] = h2m;  // 8 consecutive floats per WG
      }
    }
    __syncthreads();
    h2r[0] = h2buf[hbase + 0];
    h2r[1] = h2buf[hbase + 1];

#pragma unroll
    for (int j = 0; j < I0; ++j) xc[j] = xnx[j];
  }
}

extern "C" void kernel_launch(void* const* d_in, const int* in_sizes, int n_in,
                              void* d_out, int out_size, void* d_ws, size_t ws_size,
                              hipStream_t stream) {
  (void)in_sizes; (void)n_in; (void)d_ws; (void)ws_size; (void)out_size;
  const float* x     = (const float*)d_in[0];
  const float* w_ih0 = (const float*)d_in[1];
  const float* w_hh0 = (const float*)d_in[2];
  const float* b_ih0 = (const float*)d_in[3];
  const float* b_hh0 = (const float*)d_in[4];
  const float* w_ih1 = (const float*)d_in[5];
  const float* w_hh1 = (const float*)d_in[6];
  const float* b_ih1 = (const float*)d_in[7];
  const float* b_hh1 = (const float*)d_in[8];
  const float* w_ih2 = (const float*)d_in[9];
  const float* w_hh2 = (const float*)d_in[10];
  const float* b_ih2 = (const float*)d_in[11];
  const float* b_hh2 = (const float*)d_in[12];
  float* out = (float*)d_out;

  gru3_fused<<<NB / 4, 64, 0, stream>>>(
      x, w_ih0, w_hh0, b_ih0, b_hh0,
      w_ih1, w_hh1, b_ih1, b_hh1,
      w_ih2, w_hh2, b_ih2, b_hh2, out);
}

// Round 2
// 830.326 us; speedup vs baseline: 1.8249x; 1.8249x over previous
//
#include <hip/hip_runtime.h>

namespace {

constexpr int TT = 1024;   // timesteps
constexpr int NB = 4096;   // batch
constexpr int I0 = 5;
constexpr int H0 = 15, H1 = 10, H2 = 2;

// Pre-scales so activations use v_exp_f32 (exp2) directly:
// sigmoid(v) = 1/(1+exp2(-v*L2E)); tanh(u)=2/(1+exp2(-u*2*L2E))-1.
constexpr float L2E  = 1.44269504088896340736f;
constexpr float L2E2 = 2.88539008177792681472f;

__device__ __forceinline__ float frcp(float v) { return __builtin_amdgcn_rcpf(v); }
__device__ __forceinline__ float fexp2(float v) { return __builtin_amdgcn_exp2f(v); }
// arg already scaled by L2E
__device__ __forceinline__ float sigm_p(float v) { return frcp(1.0f + fexp2(-v)); }
// arg already scaled by 2*L2E
__device__ __forceinline__ float tanh_p(float u) {
  return 2.0f * frcp(1.0f + fexp2(-u)) - 1.0f;
}

}  // namespace

// Grid: 1024 blocks x 64 threads (4 samples x 16 hidden-slots per wave).
// 1024 waves = 1 wave/SIMD -> occupancy is capped at 12% regardless of VGPRs,
// so we spend registers freely: ALL weights (171 floats/lane) live in VGPRs.
// Layers are skewed by one timestep so there is ONE LDS exchange per step.
extern "C" __global__ __launch_bounds__(64, 1) void gru3_fused(
    const float* __restrict__ x,
    const float* __restrict__ w_ih0, const float* __restrict__ w_hh0,
    const float* __restrict__ b_ih0, const float* __restrict__ b_hh0,
    const float* __restrict__ w_ih1, const float* __restrict__ w_hh1,
    const float* __restrict__ b_ih1, const float* __restrict__ b_hh1,
    const float* __restrict__ w_ih2, const float* __restrict__ w_hh2,
    const float* __restrict__ b_ih2, const float* __restrict__ b_hh2,
    float* __restrict__ out) {
  __shared__ float h0buf[64];  // [sample(4)][16 cols], cols >= H are pads
  __shared__ float h1buf[64];
  __shared__ float h2buf[64];

  const int tid = threadIdx.x;
  const int slot = tid & 15;
  const int smp = tid >> 4;
  const int b = blockIdx.x * 4 + smp;
  const int hbase = smp << 4;

  // Clamped row per layer: extra slots duplicate the last unit (uniform
  // control flow); their exchange writes land in pad columns (never read).
  const int c0 = slot < H0 ? slot : H0 - 1;
  const int c1 = slot < H1 ? slot : H1 - 1;
  const int c2 = slot < H2 ? slot : H2 - 1;

  // ---- all weights -> registers, pre-scaled (one-time, L2-cached) ----
  float W0xr[I0], W0xz[I0], W0xn[I0];
  float W0hr[H0], W0hz[H0], W0hn[H0];
  float W1xr[H0], W1xz[H0], W1xn[H0];
  float W1hr[H1], W1hz[H1], W1hn[H1];
  float W2xr[H1], W2xz[H1], W2xn[H1];
  float W2hr[H2], W2hz[H2], W2hn[H2];

#pragma unroll
  for (int j = 0; j < I0; ++j) {
    W0xr[j] = w_ih0[c0 * I0 + j] * L2E;
    W0xz[j] = w_ih0[(H0 + c0) * I0 + j] * L2E;
    W0xn[j] = w_ih0[(2 * H0 + c0) * I0 + j] * L2E2;
  }
#pragma unroll
  for (int k = 0; k < H0; ++k) {
    W0hr[k] = w_hh0[c0 * H0 + k] * L2E;
    W0hz[k] = w_hh0[(H0 + c0) * H0 + k] * L2E;
    W0hn[k] = w_hh0[(2 * H0 + c0) * H0 + k] * L2E2;
    W1xr[k] = w_ih1[c1 * H0 + k] * L2E;
    W1xz[k] = w_ih1[(H1 + c1) * H0 + k] * L2E;
    W1xn[k] = w_ih1[(2 * H1 + c1) * H0 + k] * L2E2;
  }
#pragma unroll
  for (int k = 0; k < H1; ++k) {
    W1hr[k] = w_hh1[c1 * H1 + k] * L2E;
    W1hz[k] = w_hh1[(H1 + c1) * H1 + k] * L2E;
    W1hn[k] = w_hh1[(2 * H1 + c1) * H1 + k] * L2E2;
    W2xr[k] = w_ih2[c2 * H1 + k] * L2E;
    W2xz[k] = w_ih2[(H2 + c2) * H1 + k] * L2E;
    W2xn[k] = w_ih2[(2 * H2 + c2) * H1 + k] * L2E2;
  }
#pragma unroll
  for (int k = 0; k < H2; ++k) {
    W2hr[k] = w_hh2[c2 * H2 + k] * L2E;
    W2hz[k] = w_hh2[(H2 + c2) * H2 + k] * L2E;
    W2hn[k] = w_hh2[(2 * H2 + c2) * H2 + k] * L2E2;
  }

  const float b0r  = (b_ih0[c0] + b_hh0[c0]) * L2E;
  const float b0z  = (b_ih0[H0 + c0] + b_hh0[H0 + c0]) * L2E;
  const float b0nx = b_ih0[2 * H0 + c0] * L2E2;
  const float b0nh = b_hh0[2 * H0 + c0] * L2E2;
  const float b1r  = (b_ih1[c1] + b_hh1[c1]) * L2E;
  const float b1z  = (b_ih1[H1 + c1] + b_hh1[H1 + c1]) * L2E;
  const float b1nx = b_ih1[2 * H1 + c1] * L2E2;
  const float b1nh = b_hh1[2 * H1 + c1] * L2E2;
  const float b2r  = (b_ih2[c2] + b_hh2[c2]) * L2E;
  const float b2z  = (b_ih2[H2 + c2] + b_hh2[H2 + c2]) * L2E;
  const float b2nx = b_ih2[2 * H2 + c2] * L2E2;
  const float b2nh = b_hh2[2 * H2 + c2] * L2E2;

  // Replicated recurrent state (refreshed from LDS once per iteration) and
  // each slot's own hidden value.
  float h0r[H0], h1r[H1], h2r[H2];
#pragma unroll
  for (int k = 0; k < H0; ++k) h0r[k] = 0.0f;
#pragma unroll
  for (int k = 0; k < H1; ++k) h1r[k] = 0.0f;
#pragma unroll
  for (int k = 0; k < H2; ++k) h2r[k] = 0.0f;
  float h0m = 0.0f, h1m = 0.0f, h2m = 0.0f;

  h0buf[tid] = 0.0f;
  h1buf[tid] = 0.0f;
  h2buf[tid] = 0.0f;
  __syncthreads();

  float xc[I0];
  auto loadx = [&](int t, float* dst) {
    const float* p = x + (t * NB + b) * I0;
#pragma unroll
    for (int j = 0; j < I0; ++j) dst[j] = p[j];
  };

  auto L0 = [&]() {
    float aR = b0r, aZ = b0z, aNx = b0nx, aNh = b0nh;
#pragma unroll
    for (int j = 0; j < I0; ++j) {
      const float xv = xc[j];
      aR += W0xr[j] * xv;
      aZ += W0xz[j] * xv;
      aNx += W0xn[j] * xv;
    }
#pragma unroll
    for (int k = 0; k < H0; ++k) {
      const float h = h0r[k];
      aR += W0hr[k] * h;
      aZ += W0hz[k] * h;
      aNh += W0hn[k] * h;
    }
    const float r = sigm_p(aR);
    const float z = sigm_p(aZ);
    const float n = tanh_p(aNx + r * aNh);
    h0m = n + z * (h0m - n);
    h0buf[hbase + slot] = h0m;
  };

  auto L1 = [&]() {
    float aR = b1r, aZ = b1z, aNx = b1nx, aNh = b1nh;
#pragma unroll
    for (int k = 0; k < H0; ++k) {
      const float v = h0r[k];
      aR += W1xr[k] * v;
      aZ += W1xz[k] * v;
      aNx += W1xn[k] * v;
    }
#pragma unroll
    for (int k = 0; k < H1; ++k) {
      const float v = h1r[k];
      aR += W1hr[k] * v;
      aZ += W1hz[k] * v;
      aNh += W1hn[k] * v;
    }
    const float r = sigm_p(aR);
    const float z = sigm_p(aZ);
    const float n = tanh_p(aNx + r * aNh);
    h1m = n + z * (h1m - n);
    h1buf[hbase + slot] = h1m;
  };

  auto L2s = [&](int tt) {
    float aR = b2r, aZ = b2z, aNx = b2nx, aNh = b2nh;
#pragma unroll
    for (int k = 0; k < H1; ++k) {
      const float v = h1r[k];
      aR += W2xr[k] * v;
      aZ += W2xz[k] * v;
      aNx += W2xn[k] * v;
    }
#pragma unroll
    for (int k = 0; k < H2; ++k) {
      const float v = h2r[k];
      aR += W2hr[k] * v;
      aZ += W2hz[k] * v;
      aNh += W2hn[k] * v;
    }
    const float r = sigm_p(aR);
    const float z = sigm_p(aZ);
    const float n = tanh_p(aNx + r * aNh);
    h2m = n + z * (h2m - n);
    h2buf[hbase + slot] = h2m;
    if (slot < H2) {
      out[(tt * NB + b) * H2 + slot] = h2m;  // 8 consecutive floats per WG
    }
  };

  // One exchange per iteration: writes above, barrier, vectorized re-reads.
  auto exch = [&]() {
    __syncthreads();
    const float4 a0 = *(const float4*)&h0buf[hbase + 0];
    const float4 a1 = *(const float4*)&h0buf[hbase + 4];
    const float4 a2 = *(const float4*)&h0buf[hbase + 8];
    const float4 a3 = *(const float4*)&h0buf[hbase + 12];
    h0r[0] = a0.x;  h0r[1] = a0.y;  h0r[2] = a0.z;  h0r[3] = a0.w;
    h0r[4] = a1.x;  h0r[5] = a1.y;  h0r[6] = a1.z;  h0r[7] = a1.w;
    h0r[8] = a2.x;  h0r[9] = a2.y;  h0r[10] = a2.z; h0r[11] = a2.w;
    h0r[12] = a3.x; h0r[13] = a3.y; h0r[14] = a3.z;
    const float4 c0v = *(const float4*)&h1buf[hbase + 0];
    const float4 c1v = *(const float4*)&h1buf[hbase + 4];
    const float4 c2v = *(const float4*)&h1buf[hbase + 8];
    h1r[0] = c0v.x; h1r[1] = c0v.y; h1r[2] = c0v.z; h1r[3] = c0v.w;
    h1r[4] = c1v.x; h1r[5] = c1v.y; h1r[6] = c1v.z; h1r[7] = c1v.w;
    h1r[8] = c2v.x; h1r[9] = c2v.y;
    h2r[0] = h2buf[hbase + 0];
    h2r[1] = h2buf[hbase + 1];
    // No trailing barrier: single wave per block, DS pipe is in-order, so the
    // next iteration's writes (later in program order) can't pass these reads.
  };

  // ---- skewed pipeline: iteration i computes L0(i), L1(i-1), L2(i-2) ----
  loadx(0, xc);
  L0();                  // i = 0
  exch();
  loadx(1, xc);
  L0();                  // i = 1
  L1();
  exch();
  loadx(2, xc);

#pragma unroll 1
  for (int i = 2; i < TT; ++i) {
    float xnx[I0];
    const int tn = (i + 1 < TT) ? i + 1 : TT - 1;
    loadx(tn, xnx);      // prefetch next x while this step computes
    L0();
    L1();
    L2s(i - 2);
    exch();
#pragma unroll
    for (int j = 0; j < I0; ++j) xc[j] = xnx[j];
  }

  L1();                  // i = TT   : h1(TT-1)
  L2s(TT - 2);
  exch();
  L2s(TT - 1);           // i = TT+1 : h2(TT-1)
}

extern "C" void kernel_launch(void* const* d_in, const int* in_sizes, int n_in,
                              void* d_out, int out_size, void* d_ws, size_t ws_size,
                              hipStream_t stream) {
  (void)in_sizes; (void)n_in; (void)d_ws; (void)ws_size; (void)out_size;
  const float* x     = (const float*)d_in[0];
  const float* w_ih0 = (const float*)d_in[1];
  const float* w_hh0 = (const float*)d_in[2];
  const float* b_ih0 = (const float*)d_in[3];
  const float* b_hh0 = (const float*)d_in[4];
  const float* w_ih1 = (const float*)d_in[5];
  const float* w_hh1 = (const float*)d_in[6];
  const float* b_ih1 = (const float*)d_in[7];
  const float* b_hh1 = (const float*)d_in[8];
  const float* w_ih2 = (const float*)d_in[9];
  const float* w_hh2 = (const float*)d_in[10];
  const float* b_ih2 = (const float*)d_in[11];
  const float* b_hh2 = (const float*)d_in[12];
  float* out = (float*)d_out;

  gru3_fused<<<NB / 4, 64, 0, stream>>>(
      x, w_ih0, w_hh0, b_ih0, b_hh0,
      w_ih1, w_hh1, b_ih1, b_hh1,
      w_ih2, w_hh2, b_ih2, b_hh2, out);
}

// Round 3
// 685.385 us; speedup vs baseline: 2.2108x; 1.2115x over previous
//
#include <hip/hip_runtime.h>

namespace {

constexpr int TT = 1024;   // timesteps
constexpr int NB = 4096;   // batch
constexpr int H0 = 15, H1 = 10, H2 = 2;

// Pre-scales so activations use v_exp_f32 (exp2) directly:
// sigmoid(v) = 1/(1+exp2(-v*L2E)); tanh(u) = 2/(1+exp2(-u*2*L2E)) - 1.
constexpr float L2E  = 1.44269504088896340736f;
constexpr float L2E2 = 2.88539008177792681472f;

// Staging vector per sample (floats): x[0..4] pad[5..7] h0[8..22] pad[23]
// h1[24..33] pad[34..35] h2[36..37] pad[38..47].  Window starts (16B-aligned):
// L0 -> 0 (x+h0), L1 -> 8 (h0+h1), L2 -> 24 (h1+h2). Window = 28 floats.
constexpr int SSTRIDE = 48;
constexpr int NWINQ   = 7;    // 7 x float4

typedef float v2f __attribute__((ext_vector_type(2)));
typedef float v4f __attribute__((ext_vector_type(4)));

__device__ __forceinline__ float frcp(float v)  { return __builtin_amdgcn_rcpf(v); }
__device__ __forceinline__ float fexp2(float v) { return __builtin_amdgcn_exp2f(v); }
__device__ __forceinline__ float sigm_p(float v) { return frcp(1.0f + fexp2(-v)); }
__device__ __forceinline__ float tanh_p(float u) {
  return __builtin_fmaf(2.0f, frcp(1.0f + fexp2(-u)), -1.0f);
}

}  // namespace

// Grid: 2048 blocks x 64 threads = 2 waves/SIMD (latency hiding).
// Wave = 2 samples x 32 lanes. Per sample: lanes 0-14 = L0 units,
// 15-24 = L1 units, 25-26 = L2 units, 27-31 = x-loaders. Uniform code:
// every lane reads a 28-float window of [x|h0|h1|h2] staging and does 4
// zero-padded dots. Layers are skewed (iter i: L0(i), L1(i-1), L2(i-2)) so
// one publish per iteration suffices. Single-wave block: no __syncthreads
// needed (wave-lockstep + in-order DS pipe); wave_barrier pins ordering.
extern "C" __global__ __launch_bounds__(64, 2) void gru3_fused(
    const float* __restrict__ x,
    const float* __restrict__ w_ih0, const float* __restrict__ w_hh0,
    const float* __restrict__ b_ih0, const float* __restrict__ b_hh0,
    const float* __restrict__ w_ih1, const float* __restrict__ w_hh1,
    const float* __restrict__ b_ih1, const float* __restrict__ b_hh1,
    const float* __restrict__ w_ih2, const float* __restrict__ w_hh2,
    const float* __restrict__ b_ih2, const float* __restrict__ b_hh2,
    float* __restrict__ out) {
  // 2 samples * 48 + tail pad so L2's window over-read stays in-buffer.
  __shared__ __attribute__((aligned(16))) float stage[112];

  const int tid  = threadIdx.x;
  const int lane = tid & 31;
  const int smp  = tid >> 5;
  const int b    = blockIdx.x * 2 + smp;
  const int sbase = smp * SSTRIDE;

  int cls, u;
  if (lane < 15)      { cls = 0; u = lane; }
  else if (lane < 25) { cls = 1; u = lane - 15; }
  else if (lane < 27) { cls = 2; u = lane - 25; }
  else                { cls = 3; u = lane - 27; }   // x-loader

  const int  woff   = (cls == 0) ? 0 : (cls == 1) ? 8 : (cls == 2) ? 24 : 0;
  const int  wpos   = (cls == 0) ? 8 + u : (cls == 1) ? 24 + u
                    : (cls == 2) ? 36 + u : u;
  const int  istart = cls;            // suppress h-update until layer's first step
  const bool is_x   = (cls == 3);
  const bool is_o   = (cls == 2);
  const int  xj     = is_x ? u : 0;   // in-bounds x column for everyone

  // ---- per-lane padded weight vectors (zero outside class's inputs) ----
  float Wr[28], Wz[28], Wnx[28], Wnh[28];
#pragma unroll
  for (int j = 0; j < 28; ++j) { Wr[j] = 0.f; Wz[j] = 0.f; Wnx[j] = 0.f; Wnh[j] = 0.f; }
  float br = 0.f, bz = 0.f, bnx = 0.f, bnh = 0.f;

  if (cls == 0) {
#pragma unroll
    for (int j = 0; j < 5; ++j) {
      Wr [j] = w_ih0[(u         ) * 5 + j] * L2E;
      Wz [j] = w_ih0[(H0 + u    ) * 5 + j] * L2E;
      Wnx[j] = w_ih0[(2 * H0 + u) * 5 + j] * L2E2;
    }
#pragma unroll
    for (int k = 0; k < 15; ++k) {
      Wr [8 + k] = w_hh0[(u         ) * 15 + k] * L2E;
      Wz [8 + k] = w_hh0[(H0 + u    ) * 15 + k] * L2E;
      Wnh[8 + k] = w_hh0[(2 * H0 + u) * 15 + k] * L2E2;
    }
    br  = (b_ih0[u] + b_hh0[u]) * L2E;
    bz  = (b_ih0[H0 + u] + b_hh0[H0 + u]) * L2E;
    bnx = b_ih0[2 * H0 + u] * L2E2;
    bnh = b_hh0[2 * H0 + u] * L2E2;
  } else if (cls == 1) {
#pragma unroll
    for (int k = 0; k < 15; ++k) {
      Wr [k] = w_ih1[(u         ) * 15 + k] * L2E;
      Wz [k] = w_ih1[(H1 + u    ) * 15 + k] * L2E;
      Wnx[k] = w_ih1[(2 * H1 + u) * 15 + k] * L2E2;
    }
#pragma unroll
    for (int k = 0; k < 10; ++k) {
      Wr [16 + k] = w_hh1[(u         ) * 10 + k] * L2E;
      Wz [16 + k] = w_hh1[(H1 + u    ) * 10 + k] * L2E;
      Wnh[16 + k] = w_hh1[(2 * H1 + u) * 10 + k] * L2E2;
    }
    br  = (b_ih1[u] + b_hh1[u]) * L2E;
    bz  = (b_ih1[H1 + u] + b_hh1[H1 + u]) * L2E;
    bnx = b_ih1[2 * H1 + u] * L2E2;
    bnh = b_hh1[2 * H1 + u] * L2E2;
  } else if (cls == 2) {
#pragma unroll
    for (int k = 0; k < 10; ++k) {
      Wr [k] = w_ih2[(u         ) * 10 + k] * L2E;
      Wz [k] = w_ih2[(H2 + u    ) * 10 + k] * L2E;
      Wnx[k] = w_ih2[(2 * H2 + u) * 10 + k] * L2E2;
    }
#pragma unroll
    for (int k = 0; k < 2; ++k) {
      Wr [12 + k] = w_hh2[(u         ) * 2 + k] * L2E;
      Wz [12 + k] = w_hh2[(H2 + u    ) * 2 + k] * L2E;
      Wnh[12 + k] = w_hh2[(2 * H2 + u) * 2 + k] * L2E2;
    }
    br  = (b_ih2[u] + b_hh2[u]) * L2E;
    bz  = (b_ih2[H2 + u] + b_hh2[H2 + u]) * L2E;
    bnx = b_ih2[2 * H2 + u] * L2E2;
    bnh = b_hh2[2 * H2 + u] * L2E2;
  }

  // pack to float2 for v_pk_fma_f32
  v2f Wr2[14], Wz2[14], Wnx2[14], Wnh2[14];
#pragma unroll
  for (int j = 0; j < 14; ++j) {
    Wr2 [j] = (v2f){Wr [2 * j], Wr [2 * j + 1]};
    Wz2 [j] = (v2f){Wz [2 * j], Wz [2 * j + 1]};
    Wnx2[j] = (v2f){Wnx[2 * j], Wnx[2 * j + 1]};
    Wnh2[j] = (v2f){Wnh[2 * j], Wnh[2 * j + 1]};
  }

  // ---- init staging (zeros = h(-1) states + pads), publish x(0) ----
  for (int j = tid; j < 112; j += 64) stage[j] = 0.0f;

  float xw, xn;   // x publish pipeline: xw = x(i+1), xn = x(i+2)
  {
    const int base = b * 5 + xj;
    const float x0 = x[base];                 // t=0
    xw = x[NB * 5 + base];                    // t=1
    xn = x[2 * NB * 5 + base];                // t=2
    if (is_x) stage[sbase + u] = x0;
  }
  __builtin_amdgcn_wave_barrier();

  float h = 0.0f;
  const v4f* wloc = (const v4f*)&stage[sbase + woff];

#pragma unroll 1
  for (int i = 0; i <= TT + 1; ++i) {
    // window read (sees previous iteration's publishes; in-order DS pipe)
    v4f q0 = wloc[0], q1 = wloc[1], q2 = wloc[2], q3 = wloc[3];
    v4f q4 = wloc[4], q5 = wloc[5], q6 = wloc[6];

    // prefetch x(i+3) (uniform-issue; only x-lanes consume)
    int tl = i + 3; tl = tl < TT ? tl : TT - 1;
    const float xldv = x[(tl * NB + b) * 5 + xj];

    const v2f wv[14] = {q0.lo, q0.hi, q1.lo, q1.hi, q2.lo, q2.hi, q3.lo,
                        q3.hi, q4.lo, q4.hi, q5.lo, q5.hi, q6.lo, q6.hi};

    v2f aR  = (v2f){br,  0.f};
    v2f aZ  = (v2f){bz,  0.f};
    v2f aNx = (v2f){bnx, 0.f};
    v2f aNh = (v2f){bnh, 0.f};
#pragma unroll
    for (int j = 0; j < 14; ++j) {
      aR  = __builtin_elementwise_fma(Wr2 [j], wv[j], aR);
      aZ  = __builtin_elementwise_fma(Wz2 [j], wv[j], aZ);
      aNx = __builtin_elementwise_fma(Wnx2[j], wv[j], aNx);
      aNh = __builtin_elementwise_fma(Wnh2[j], wv[j], aNh);
    }
    const float r = sigm_p(aR.x + aR.y);
    const float z = sigm_p(aZ.x + aZ.y);
    const float n = tanh_p((aNx.x + aNx.y) + r * (aNh.x + aNh.y));
    const float hnew = n + z * (h - n);
    h = (i >= istart) ? hnew : h;       // junk-suppress before layer's first step

    stage[sbase + wpos] = is_x ? xw : h;   // publish h (units) or x(i+1) (loaders)

    if (is_o && i >= 2) {
      out[((i - 2) * NB + b) * H2 + u] = h;   // t = i-2
    }

    xw = xn;
    xn = xldv;
    __builtin_amdgcn_wave_barrier();   // keep next iter's reads after publishes
  }
}

extern "C" void kernel_launch(void* const* d_in, const int* in_sizes, int n_in,
                              void* d_out, int out_size, void* d_ws, size_t ws_size,
                              hipStream_t stream) {
  (void)in_sizes; (void)n_in; (void)d_ws; (void)ws_size; (void)out_size;
  const float* x     = (const float*)d_in[0];
  const float* w_ih0 = (const float*)d_in[1];
  const float* w_hh0 = (const float*)d_in[2];
  const float* b_ih0 = (const float*)d_in[3];
  const float* b_hh0 = (const float*)d_in[4];
  const float* w_ih1 = (const float*)d_in[5];
  const float* w_hh1 = (const float*)d_in[6];
  const float* b_ih1 = (const float*)d_in[7];
  const float* b_hh1 = (const float*)d_in[8];
  const float* w_ih2 = (const float*)d_in[9];
  const float* w_hh2 = (const float*)d_in[10];
  const float* b_ih2 = (const float*)d_in[11];
  const float* b_hh2 = (const float*)d_in[12];
  float* out = (float*)d_out;

  gru3_fused<<<NB / 2, 64, 0, stream>>>(
      x, w_ih0, w_hh0, b_ih0, b_hh0,
      w_ih1, w_hh1, b_ih1, b_hh1,
      w_ih2, w_hh2, b_ih2, b_hh2, out);
}

// Round 4
// 660.713 us; speedup vs baseline: 2.2934x; 1.0373x over previous
//
#include <hip/hip_runtime.h>

namespace {

constexpr int TT = 1024;   // timesteps
constexpr int NB = 4096;   // batch
constexpr int H0 = 15, H1 = 10, H2 = 2;

// Pre-scales so activations use v_exp_f32 (exp2) directly:
// sigmoid(v) = 1/(1+exp2(-v*L2E)); tanh(u) = 2/(1+exp2(-u*2*L2E)) - 1.
constexpr float L2E  = 1.44269504088896340736f;
constexpr float L2E2 = 2.88539008177792681472f;

// Staging vector per sample (floats): x[0..4] pad[5..7] h0[8..22] pad[23]
// h1[24..33] pad[34..35] h2[36..37] pad[38..47].  Window starts (16B-aligned):
// L0 -> 0 (x+h0), L1 -> 8 (h0+h1), L2 -> 24 (h1+h2). Window = 28 floats.
constexpr int SSTRIDE = 48;

typedef float v2f __attribute__((ext_vector_type(2)));
typedef float v4f __attribute__((ext_vector_type(4)));

__device__ __forceinline__ float frcp(float v)  { return __builtin_amdgcn_rcpf(v); }
__device__ __forceinline__ float fexp2(float v) { return __builtin_amdgcn_exp2f(v); }
__device__ __forceinline__ float sigm_p(float v) { return frcp(1.0f + fexp2(-v)); }
__device__ __forceinline__ float tanh_p(float u) {
  return __builtin_fmaf(2.0f, frcp(1.0f + fexp2(-u)), -1.0f);
}

// Guaranteed packed FMA: d = a*b + c on both halves (v_pk_fma_f32).
__device__ __forceinline__ v2f pk_fma(v2f a, v2f b, v2f c) {
  v2f d;
  asm("v_pk_fma_f32 %0, %1, %2, %3" : "=v"(d) : "v"(a), "v"(b), "v"(c));
  return d;
}

}  // namespace

// Grid: 2048 blocks x 64 threads = 2 waves/SIMD. Wave = 2 samples x 32 lanes.
// Per sample: lanes 0-14 = L0 units, 15-24 = L1 units, 25-26 = L2 units,
// 27-31 = x-loaders. Uniform code: every lane reads a 28-float window of
// [x|h0|h1|h2] staging and does 4 zero-padded dots as 56 v_pk_fma_f32.
// Layers skewed (iter i: L0(i), L1(i-1), L2(i-2)) -> one publish/iteration.
// Single-wave block: no __syncthreads (wave-lockstep + in-order DS pipe);
// wave_barrier pins compiler ordering.
extern "C" __global__ __launch_bounds__(64, 2) void gru3_fused(
    const float* __restrict__ x,
    const float* __restrict__ w_ih0, const float* __restrict__ w_hh0,
    const float* __restrict__ b_ih0, const float* __restrict__ b_hh0,
    const float* __restrict__ w_ih1, const float* __restrict__ w_hh1,
    const float* __restrict__ b_ih1, const float* __restrict__ b_hh1,
    const float* __restrict__ w_ih2, const float* __restrict__ w_hh2,
    const float* __restrict__ b_ih2, const float* __restrict__ b_hh2,
    float* __restrict__ out) {
  // 2 samples * 48 + tail pad so L2's window over-read stays in-buffer.
  __shared__ __attribute__((aligned(16))) float stage[112];

  const int tid  = threadIdx.x;
  const int lane = tid & 31;
  const int smp  = tid >> 5;
  const int b    = blockIdx.x * 2 + smp;
  const int sbase = smp * SSTRIDE;

  int cls, u;
  if (lane < 15)      { cls = 0; u = lane; }
  else if (lane < 25) { cls = 1; u = lane - 15; }
  else if (lane < 27) { cls = 2; u = lane - 25; }
  else                { cls = 3; u = lane - 27; }   // x-loader

  const int  woff   = (cls == 0) ? 0 : (cls == 1) ? 8 : (cls == 2) ? 24 : 0;
  const int  wpos   = (cls == 0) ? 8 + u : (cls == 1) ? 24 + u
                    : (cls == 2) ? 36 + u : u;
  const int  istart = cls;            // suppress h-update until layer's first step
  const bool is_x   = (cls == 3);
  const bool is_o   = (cls == 2);
  const int  xj     = is_x ? u : 0;   // in-bounds x column for everyone

  // ---- per-lane padded weight vectors (zero outside class's inputs) ----
  float Wr[28], Wz[28], Wnx[28], Wnh[28];
#pragma unroll
  for (int j = 0; j < 28; ++j) { Wr[j] = 0.f; Wz[j] = 0.f; Wnx[j] = 0.f; Wnh[j] = 0.f; }
  float br = 0.f, bz = 0.f, bnx = 0.f, bnh = 0.f;

  if (cls == 0) {
#pragma unroll
    for (int j = 0; j < 5; ++j) {
      Wr [j] = w_ih0[(u         ) * 5 + j] * L2E;
      Wz [j] = w_ih0[(H0 + u    ) * 5 + j] * L2E;
      Wnx[j] = w_ih0[(2 * H0 + u) * 5 + j] * L2E2;
    }
#pragma unroll
    for (int k = 0; k < 15; ++k) {
      Wr [8 + k] = w_hh0[(u         ) * 15 + k] * L2E;
      Wz [8 + k] = w_hh0[(H0 + u    ) * 15 + k] * L2E;
      Wnh[8 + k] = w_hh0[(2 * H0 + u) * 15 + k] * L2E2;
    }
    br  = (b_ih0[u] + b_hh0[u]) * L2E;
    bz  = (b_ih0[H0 + u] + b_hh0[H0 + u]) * L2E;
    bnx = b_ih0[2 * H0 + u] * L2E2;
    bnh = b_hh0[2 * H0 + u] * L2E2;
  } else if (cls == 1) {
#pragma unroll
    for (int k = 0; k < 15; ++k) {
      Wr [k] = w_ih1[(u         ) * 15 + k] * L2E;
      Wz [k] = w_ih1[(H1 + u    ) * 15 + k] * L2E;
      Wnx[k] = w_ih1[(2 * H1 + u) * 15 + k] * L2E2;
    }
#pragma unroll
    for (int k = 0; k < 10; ++k) {
      Wr [16 + k] = w_hh1[(u         ) * 10 + k] * L2E;
      Wz [16 + k] = w_hh1[(H1 + u    ) * 10 + k] * L2E;
      Wnh[16 + k] = w_hh1[(2 * H1 + u) * 10 + k] * L2E2;
    }
    br  = (b_ih1[u] + b_hh1[u]) * L2E;
    bz  = (b_ih1[H1 + u] + b_hh1[H1 + u]) * L2E;
    bnx = b_ih1[2 * H1 + u] * L2E2;
    bnh = b_hh1[2 * H1 + u] * L2E2;
  } else if (cls == 2) {
#pragma unroll
    for (int k = 0; k < 10; ++k) {
      Wr [k] = w_ih2[(u         ) * 10 + k] * L2E;
      Wz [k] = w_ih2[(H2 + u    ) * 10 + k] * L2E;
      Wnx[k] = w_ih2[(2 * H2 + u) * 10 + k] * L2E2;
    }
#pragma unroll
    for (int k = 0; k < 2; ++k) {
      Wr [12 + k] = w_hh2[(u         ) * 2 + k] * L2E;
      Wz [12 + k] = w_hh2[(H2 + u    ) * 2 + k] * L2E;
      Wnh[12 + k] = w_hh2[(2 * H2 + u) * 2 + k] * L2E2;
    }
    br  = (b_ih2[u] + b_hh2[u]) * L2E;
    bz  = (b_ih2[H2 + u] + b_hh2[H2 + u]) * L2E;
    bnx = b_ih2[2 * H2 + u] * L2E2;
    bnh = b_hh2[2 * H2 + u] * L2E2;
  }

  // pack to float2 for v_pk_fma_f32
  v2f Wr2[14], Wz2[14], Wnx2[14], Wnh2[14];
#pragma unroll
  for (int j = 0; j < 14; ++j) {
    Wr2 [j] = (v2f){Wr [2 * j], Wr [2 * j + 1]};
    Wz2 [j] = (v2f){Wz [2 * j], Wz [2 * j + 1]};
    Wnx2[j] = (v2f){Wnx[2 * j], Wnx[2 * j + 1]};
    Wnh2[j] = (v2f){Wnh[2 * j], Wnh[2 * j + 1]};
  }

  // ---- init staging (zeros = h(-1) states + pads), publish x(0) ----
  for (int j = tid; j < 112; j += 64) stage[j] = 0.0f;

  float xw, xn;   // x publish pipeline: xw = x(i+1), xn = x(i+2)
  {
    const int base = b * 5 + xj;
    const float x0 = x[base];                 // t=0
    xw = x[NB * 5 + base];                    // t=1
    xn = x[2 * NB * 5 + base];                // t=2
    if (is_x) stage[sbase + u] = x0;
  }
  __builtin_amdgcn_wave_barrier();

  float h = 0.0f;
  const v4f* wloc = (const v4f*)&stage[sbase + woff];
  float* pub = &stage[sbase + wpos];

  // Strength-reduced pointers: x prefetch (x(i+3), clamped) and out store.
  const float* xp = x + ((size_t)3 * NB + b) * 5 + xj;
  const size_t xstep = (size_t)NB * 5;
  float* op = out + (size_t)b * H2 + (is_o ? u : 0);  // t = i-2 target
  const size_t ostep = (size_t)NB * H2;

#pragma unroll 1
  for (int i = 0; i <= TT + 1; ++i) {
    // window read (sees previous iteration's publishes; in-order DS pipe)
    const v4f q0 = wloc[0], q1 = wloc[1], q2 = wloc[2], q3 = wloc[3];
    const v4f q4 = wloc[4], q5 = wloc[5], q6 = wloc[6];

    // prefetch x(i+3) (uniform-issue; only x-lanes consume)
    const float xldv = *xp;
    if (i + 4 < TT) xp += xstep;    // uniform scalar condition

    v2f aR  = (v2f){br,  0.f};
    v2f aZ  = (v2f){bz,  0.f};
    v2f aNx = (v2f){bnx, 0.f};
    v2f aNh = (v2f){bnh, 0.f};
#define GRU_DOT2(J, QH)               \
    aR  = pk_fma(Wr2 [J], (QH), aR);  \
    aZ  = pk_fma(Wz2 [J], (QH), aZ);  \
    aNx = pk_fma(Wnx2[J], (QH), aNx); \
    aNh = pk_fma(Wnh2[J], (QH), aNh);
    GRU_DOT2(0,  q0.lo)
    GRU_DOT2(1,  q0.hi)
    GRU_DOT2(2,  q1.lo)
    GRU_DOT2(3,  q1.hi)
    GRU_DOT2(4,  q2.lo)
    GRU_DOT2(5,  q2.hi)
    GRU_DOT2(6,  q3.lo)
    GRU_DOT2(7,  q3.hi)
    GRU_DOT2(8,  q4.lo)
    GRU_DOT2(9,  q4.hi)
    GRU_DOT2(10, q5.lo)
    GRU_DOT2(11, q5.hi)
    GRU_DOT2(12, q6.lo)
    GRU_DOT2(13, q6.hi)
#undef GRU_DOT2

    const float r = sigm_p(aR.x + aR.y);
    const float z = sigm_p(aZ.x + aZ.y);
    const float n = tanh_p((aNx.x + aNx.y) + r * (aNh.x + aNh.y));
    const float hnew = n + z * (h - n);
    h = (i >= istart) ? hnew : h;       // junk-suppress before layer's first step

    *pub = is_x ? xw : h;               // publish h (units) or x(i+1) (loaders)

    if (i >= 2) {                       // uniform branch
      if (is_o) *op = h;                // t = i-2, exec-masked
      op += ostep;
    }

    xw = xn;
    xn = xldv;
    __builtin_amdgcn_wave_barrier();    // keep next iter's reads after publishes
  }
}

extern "C" void kernel_launch(void* const* d_in, const int* in_sizes, int n_in,
                              void* d_out, int out_size, void* d_ws, size_t ws_size,
                              hipStream_t stream) {
  (void)in_sizes; (void)n_in; (void)d_ws; (void)ws_size; (void)out_size;
  const float* x     = (const float*)d_in[0];
  const float* w_ih0 = (const float*)d_in[1];
  const float* w_hh0 = (const float*)d_in[2];
  const float* b_ih0 = (const float*)d_in[3];
  const float* b_hh0 = (const float*)d_in[4];
  const float* w_ih1 = (const float*)d_in[5];
  const float* w_hh1 = (const float*)d_in[6];
  const float* b_ih1 = (const float*)d_in[7];
  const float* b_hh1 = (const float*)d_in[8];
  const float* w_ih2 = (const float*)d_in[9];
  const float* w_hh2 = (const float*)d_in[10];
  const float* b_ih2 = (const float*)d_in[11];
  const float* b_hh2 = (const float*)d_in[12];
  float* out = (float*)d_out;

  gru3_fused<<<NB / 2, 64, 0, stream>>>(
      x, w_ih0, w_hh0, b_ih0, b_hh0,
      w_ih1, w_hh1, b_ih1, b_hh1,
      w_ih2, w_hh2, b_ih2, b_hh2, out);
}